// Round 3
// baseline (359.584 us; speedup 1.0000x reference)
//
#include <hip/hip_runtime.h>
#include <hip/hip_bf16.h>
#include <cstdint>
#include <cstddef>

#define BN 8192

typedef short bf16x8 __attribute__((ext_vector_type(8)));
typedef float f32x4 __attribute__((ext_vector_type(4)));

// ---- workspace layout: bf16 weight packs, B^T layout [n][k] unless noted ----
#define O_WINT   0         // [256][256]
#define O_GKT    65536     // [768][256]
#define O_GRKT   262144    // [768][256]
#define O_WQT    458752    // [256][256]
#define O_WK     524288    // native [d][h*64+dk]
#define O_WVT    589824    // [(h,dk)=256][256]
#define O_WOT    655360    // [256][256]
#define O_WCTXT  720896    // [256][256]
#define O_WGT    786432    // [256][512]
#define O_WMT    917504    // [256][256]
#define W_TOTAL  983040

// LDS strides (element units). All rows 16B-aligned; row-stride mod 128B = 16B
// -> consecutive r16 rows land on banks offset by 4 words => <=2-way conflict (free, m136).
#define SZS  264   // shorts: sZ / sC tiles [16][264]
#define SGOS 260   // floats: gru_out fp32 [16][260]
#define SQS  1032  // shorts: qk/wmem [16][1032]
#define SFS  260   // floats: sF (aliases sQK buffer)

__device__ __forceinline__ short f2bf(float x){
  unsigned u = __builtin_bit_cast(unsigned, x);
  u = (u + 0x7fffu + ((u >> 16) & 1u)) >> 16;
  return (short)u;
}
__device__ __forceinline__ float bf2f(short s){
  unsigned u = ((unsigned)(unsigned short)s) << 16;
  return __builtin_bit_cast(float, u);
}
__device__ __forceinline__ float sigm(float x){ return 1.f/(1.f+__expf(-x)); }
__device__ __forceinline__ float tanh_(float x){
  x = fminf(20.f, fmaxf(-20.f, x));
  float e = __expf(-2.f*x);
  return (1.f - e)/(1.f + e);
}
__device__ __forceinline__ f32x4 mfma16(bf16x8 a, bf16x8 b, f32x4 c){
  return __builtin_amdgcn_mfma_f32_16x16x32_bf16(a, b, c, 0, 0, 0);
}
// 8 consecutive fp32 -> bf16 frag (works for global or LDS pointers)
__device__ __forceinline__ bf16x8 frag_f32(const float* p){
  float4 a = *reinterpret_cast<const float4*>(p);
  float4 b = *reinterpret_cast<const float4*>(p+4);
  bf16x8 v;
  v[0]=f2bf(a.x); v[1]=f2bf(a.y); v[2]=f2bf(a.z); v[3]=f2bf(a.w);
  v[4]=f2bf(b.x); v[5]=f2bf(b.y); v[6]=f2bf(b.z); v[7]=f2bf(b.w);
  return v;
}

// ============================ K0: weight pack ============================
__global__ __launch_bounds__(256) void k_prep(
    const float* __restrict__ W_in, const float* __restrict__ gru_k,
    const float* __restrict__ gru_rk, const float* __restrict__ Wq,
    const float* __restrict__ Wk, const float* __restrict__ Wv,
    const float* __restrict__ Wo, const float* __restrict__ W_ctx,
    const float* __restrict__ W_gate, const float* __restrict__ W_mem,
    short* __restrict__ wp)
{
  int idx = blockIdx.x*256 + threadIdx.x;
  if (idx < 65536){ int n=idx>>8, k=idx&255; wp[O_WINT+idx]=f2bf(W_in[k*256+n]); return; }
  idx -= 65536;
  if (idx < 196608){ int n=idx>>8, k=idx&255; wp[O_GKT+idx]=f2bf(gru_k[k*768+n]); return; }
  idx -= 196608;
  if (idx < 196608){ int n=idx>>8, k=idx&255; wp[O_GRKT+idx]=f2bf(gru_rk[k*768+n]); return; }
  idx -= 196608;
  if (idx < 65536){ int n=idx>>8, k=idx&255; wp[O_WQT+idx]=f2bf(Wq[k*256+n]); return; }
  idx -= 65536;
  if (idx < 65536){ wp[O_WK+idx]=f2bf(Wk[idx]); return; }
  idx -= 65536;
  if (idx < 65536){ int n=idx>>8, k=idx&255; wp[O_WVT+idx]=f2bf(Wv[k*256+n]); return; }
  idx -= 65536;
  if (idx < 65536){ int n=idx>>8, k=idx&255; wp[O_WOT+idx]=f2bf(Wo[k*256+n]); return; }
  idx -= 65536;
  if (idx < 65536){ int n=idx>>8, k=idx&255; wp[O_WCTXT+idx]=f2bf(W_ctx[k*256+n]); return; }
  idx -= 65536;
  if (idx < 131072){ int n=idx>>9, k=idx&511; wp[O_WGT+idx]=f2bf(W_gate[k*256+n]); return; }
  idx -= 131072;
  if (idx < 65536){ int n=idx>>8, k=idx&255; wp[O_WMT+idx]=f2bf(W_mem[k*256+n]); }
}

// =================== K1: fully fused cell, 16 rows/block ===================
__global__ __launch_bounds__(256) void k_fused(
    const float* __restrict__ inputs, const float* __restrict__ h_prev,
    const float* __restrict__ mem,
    const float* __restrict__ b_in, const float* __restrict__ gru_b,
    const float* __restrict__ bq, const float* __restrict__ b_mem,
    const float* __restrict__ bv, const float* __restrict__ bo,
    const float* __restrict__ g_attn, const float* __restrict__ beta_attn,
    const float* __restrict__ b_ctx, const float* __restrict__ b_gate,
    const float* __restrict__ g_out, const float* __restrict__ beta_out,
    const short* __restrict__ wp, float* __restrict__ d_out)
{
  const int tid = threadIdx.x;
  const int wv = tid >> 6, lane = tid & 63;
  const int r16 = lane & 15, kk = (lane >> 4) * 8, vr4 = (lane >> 4) * 4;
  const int row0 = blockIdx.x * 16;
  const int cb = wv * 64;

  __shared__ __attribute__((aligned(16))) short sZ[16*SZS];   // z_t -> q -> ctx -> ctx_ln -> ctx_p
  __shared__ __attribute__((aligned(16))) float sGO[16*SGOS]; // gru_out fp32
  __shared__ __attribute__((aligned(16))) short sQK[16*SQS];  // qk -> wmem; aliased by sF
  float* sF = (float*)sQK;                                    // fp32 scratch (context / h_pre)

  // ---- Phase A: z_t = inputs @ W_in + b_in -> sZ (bf16)
  {
    f32x4 acc[4] = {};
    for (int k0=0; k0<256; k0+=32){
      bf16x8 a = frag_f32(inputs + (size_t)(row0+r16)*256 + k0 + kk);
      #pragma unroll
      for (int ct=0; ct<4; ct++){
        bf16x8 b = *reinterpret_cast<const bf16x8*>(wp + O_WINT + (cb+ct*16+r16)*256 + k0 + kk);
        acc[ct] = mfma16(a, b, acc[ct]);
      }
    }
    #pragma unroll
    for (int ct=0; ct<4; ct++)
      #pragma unroll
      for (int v=0; v<4; v++){
        int col = cb + ct*16 + r16;
        sZ[(vr4+v)*SZS + col] = f2bf(acc[ct][v] + b_in[col]);
      }
  }
  __syncthreads();

  // ---- Phase B: new_entry = z_t @ W_mem + b_mem -> out memory slot 9
  {
    f32x4 acc[4] = {};
    for (int k0=0; k0<256; k0+=32){
      bf16x8 a = *reinterpret_cast<const bf16x8*>(sZ + r16*SZS + k0 + kk);
      #pragma unroll
      for (int ct=0; ct<4; ct++){
        bf16x8 b = *reinterpret_cast<const bf16x8*>(wp + O_WMT + (cb+ct*16+r16)*256 + k0 + kk);
        acc[ct] = mfma16(a, b, acc[ct]);
      }
    }
    float* om = d_out + (size_t)BN*256;
    #pragma unroll
    for (int ct=0; ct<4; ct++)
      #pragma unroll
      for (int v=0; v<4; v++){
        int col = cb + ct*16 + r16;
        om[(size_t)(row0+vr4+v)*2560 + 2304 + col] = acc[ct][v] + b_mem[col];
      }
  }

  // ---- Phase C: GRU (reset_after) -> sGO (fp32 LDS)
  #pragma unroll
  for (int ct=0; ct<4; ct++){
    const int c = cb + ct*16;
    f32x4 az = {}, arr = {}, ax = {}, ah = {};
    for (int k0=0; k0<256; k0+=32){
      bf16x8 aZ = *reinterpret_cast<const bf16x8*>(sZ + r16*SZS + k0 + kk);
      bf16x8 aH = frag_f32(h_prev + (size_t)(row0+r16)*256 + k0 + kk);
      bf16x8 bz1 = *reinterpret_cast<const bf16x8*>(wp + O_GKT  + (c      +r16)*256 + k0 + kk);
      bf16x8 br1 = *reinterpret_cast<const bf16x8*>(wp + O_GKT  + (256+c  +r16)*256 + k0 + kk);
      bf16x8 bx1 = *reinterpret_cast<const bf16x8*>(wp + O_GKT  + (512+c  +r16)*256 + k0 + kk);
      bf16x8 bz2 = *reinterpret_cast<const bf16x8*>(wp + O_GRKT + (c      +r16)*256 + k0 + kk);
      bf16x8 br2 = *reinterpret_cast<const bf16x8*>(wp + O_GRKT + (256+c  +r16)*256 + k0 + kk);
      bf16x8 bh2 = *reinterpret_cast<const bf16x8*>(wp + O_GRKT + (512+c  +r16)*256 + k0 + kk);
      az  = mfma16(aZ, bz1, az);  az  = mfma16(aH, bz2, az);
      arr = mfma16(aZ, br1, arr); arr = mfma16(aH, br2, arr);
      ax  = mfma16(aZ, bx1, ax);
      ah  = mfma16(aH, bh2, ah);
    }
    #pragma unroll
    for (int v=0; v<4; v++){
      int lrow = vr4 + v, grow = row0 + lrow, col = c + r16;
      float z  = sigm(az[v]  + gru_b[col]     + gru_b[768+col]);
      float r  = sigm(arr[v] + gru_b[256+col] + gru_b[768+256+col]);
      float hc = tanh_(ax[v] + gru_b[512+col] + r*(ah[v] + gru_b[768+512+col]));
      float hp = h_prev[(size_t)grow*256 + col];
      sGO[lrow*SGOS + col] = z*hp + (1.f - z)*hc;
    }
  }
  __syncthreads();   // sGO ready; all reads of sZ(z_t) done

  // ---- Phase D: q = gru_out @ Wq + bq -> sZ (reuse)
  {
    f32x4 acc[4] = {};
    for (int k0=0; k0<256; k0+=32){
      bf16x8 a = frag_f32(sGO + r16*SGOS + k0 + kk);
      #pragma unroll
      for (int ct=0; ct<4; ct++){
        bf16x8 b = *reinterpret_cast<const bf16x8*>(wp + O_WQT + (cb+ct*16+r16)*256 + k0 + kk);
        acc[ct] = mfma16(a, b, acc[ct]);
      }
    }
    #pragma unroll
    for (int ct=0; ct<4; ct++)
      #pragma unroll
      for (int v=0; v<4; v++){
        int col = cb + ct*16 + r16;
        sZ[(vr4+v)*SZS + col] = f2bf(acc[ct][v] + bq[col]);
      }
  }
  __syncthreads();

  // ---- Phase E: qk_h = q_h @ Wk_h^T (head = wv) -> sQK bf16 [16][4*256]
  for (int nb=0; nb<4; nb++){
    f32x4 acc[4] = {};
    #pragma unroll
    for (int k0=0; k0<64; k0+=32){
      bf16x8 a = *reinterpret_cast<const bf16x8*>(sZ + r16*SZS + wv*64 + k0 + kk);
      #pragma unroll
      for (int ct=0; ct<4; ct++){
        bf16x8 b = *reinterpret_cast<const bf16x8*>(wp + O_WK + (nb*64+ct*16+r16)*256 + wv*64 + k0 + kk);
        acc[ct] = mfma16(a, b, acc[ct]);
      }
    }
    #pragma unroll
    for (int ct=0; ct<4; ct++)
      #pragma unroll
      for (int v=0; v<4; v++){
        int d = nb*64 + ct*16 + r16;
        sQK[(vr4+v)*SQS + wv*256 + d] = f2bf(acc[ct][v]);
      }
  }
  __syncthreads();

  // ---- Phase F: scores/softmax/wmem + memory shift (4 rows per wave)
  for (int i=0; i<4; i++){
    const int rr = wv*4 + i;
    const float* mrow = mem + (size_t)(row0+rr)*2560;
    float* orow = d_out + (size_t)BN*256 + (size_t)(row0+rr)*2560;

    float qv[4][4];
    #pragma unroll
    for (int h=0; h<4; h++){
      short4 s = *reinterpret_cast<const short4*>(sQK + rr*SQS + h*256 + lane*4);
      qv[h][0]=bf2f(s.x); qv[h][1]=bf2f(s.y); qv[h][2]=bf2f(s.z); qv[h][3]=bf2f(s.w);
    }
    float4 mv[10];
    float sc[10][4];
    #pragma unroll
    for (int m=0; m<10; m++){
      mv[m] = *reinterpret_cast<const float4*>(mrow + m*256 + lane*4);
      if (m >= 1) *reinterpret_cast<float4*>(orow + (m-1)*256 + lane*4) = mv[m];  // shift
      #pragma unroll
      for (int h=0; h<4; h++){
        float p = qv[h][0]*mv[m].x + qv[h][1]*mv[m].y + qv[h][2]*mv[m].z + qv[h][3]*mv[m].w;
        p += __shfl_xor(p,32); p += __shfl_xor(p,16); p += __shfl_xor(p,8);
        p += __shfl_xor(p,4);  p += __shfl_xor(p,2);  p += __shfl_xor(p,1);
        sc[m][h] = p * 0.125f;
      }
    }
    #pragma unroll
    for (int h=0; h<4; h++){
      float mx = sc[0][h];
      #pragma unroll
      for (int m=1; m<10; m++) mx = fmaxf(mx, sc[m][h]);
      float s = 0.f;
      #pragma unroll
      for (int m=0; m<10; m++){ float e = __expf(sc[m][h]-mx); sc[m][h]=e; s+=e; }
      float inv = 1.f/s;
      #pragma unroll
      for (int m=0; m<10; m++) sc[m][h] *= inv;
    }
    float w4[4][4] = {};
    #pragma unroll
    for (int m=0; m<10; m++)
      #pragma unroll
      for (int h=0; h<4; h++){
        w4[h][0] += sc[m][h]*mv[m].x; w4[h][1] += sc[m][h]*mv[m].y;
        w4[h][2] += sc[m][h]*mv[m].z; w4[h][3] += sc[m][h]*mv[m].w;
      }
    #pragma unroll
    for (int h=0; h<4; h++){
      short4 o; o.x=f2bf(w4[h][0]); o.y=f2bf(w4[h][1]); o.z=f2bf(w4[h][2]); o.w=f2bf(w4[h][3]);
      *reinterpret_cast<short4*>(sQK + rr*SQS + h*256 + lane*4) = o;  // wmem over dead qk
    }
  }
  __syncthreads();

  // ---- Phase G: ctx_h = wmem_h @ Wv_h + bv (head = wv) -> sZ (as sC)
  {
    f32x4 acc[4] = {};
    for (int k0=0; k0<256; k0+=32){
      bf16x8 a = *reinterpret_cast<const bf16x8*>(sQK + r16*SQS + wv*256 + k0 + kk);
      #pragma unroll
      for (int ct=0; ct<4; ct++){
        bf16x8 b = *reinterpret_cast<const bf16x8*>(wp + O_WVT + (cb+ct*16+r16)*256 + k0 + kk);
        acc[ct] = mfma16(a, b, acc[ct]);
      }
    }
    #pragma unroll
    for (int ct=0; ct<4; ct++)
      #pragma unroll
      for (int v=0; v<4; v++){
        int col = cb + ct*16 + r16;
        sZ[(vr4+v)*SZS + col] = f2bf(acc[ct][v] + bv[col]);
      }
  }
  __syncthreads();

  // ---- Phase H: context = ctx @ Wo + bo -> sF (fp32; aliases sQK, wmem dead)
  {
    f32x4 acc[4] = {};
    for (int k0=0; k0<256; k0+=32){
      bf16x8 a = *reinterpret_cast<const bf16x8*>(sZ + r16*SZS + k0 + kk);
      #pragma unroll
      for (int ct=0; ct<4; ct++){
        bf16x8 b = *reinterpret_cast<const bf16x8*>(wp + O_WOT + (cb+ct*16+r16)*256 + k0 + kk);
        acc[ct] = mfma16(a, b, acc[ct]);
      }
    }
    __syncthreads();   // all G-era reads of sQK done before overwriting via sF
    #pragma unroll
    for (int ct=0; ct<4; ct++)
      #pragma unroll
      for (int v=0; v<4; v++){
        int col = cb + ct*16 + r16;
        sF[(vr4+v)*SFS + col] = acc[ct][v] + bo[col];
      }
  }
  __syncthreads();

  // ---- LN1 (wave-local: 16 lanes per row) : sF -> sZ (bf16 ctx_ln)
  {
    int r = tid >> 4, q = tid & 15;           // row r handled by 16 lanes of one wave
    float s1=0.f, s2=0.f;
    #pragma unroll
    for (int ii=0; ii<16; ii++){ float v = sF[r*SFS + q*16 + ii]; s1+=v; s2+=v*v; }
    #pragma unroll
    for (int off=8; off; off>>=1){ s1 += __shfl_xor(s1,off); s2 += __shfl_xor(s2,off); }
    float mu = s1*(1.f/256.f);
    float rs = rsqrtf(fmaxf(s2*(1.f/256.f) - mu*mu, 0.f) + 1e-3f);
    #pragma unroll
    for (int ii=0; ii<16; ii++){
      int c = q*16 + ii;
      sZ[r*SZS + c] = f2bf((sF[r*SFS + c]-mu)*rs*g_attn[c] + beta_attn[c]);
    }
  }
  __syncthreads();

  // ---- Phase I: ctx_p = tanh(ctx_ln @ W_ctx + b_ctx) -> regs, then sZ
  f32x4 cpv[4];
  {
    f32x4 acc[4] = {};
    for (int k0=0; k0<256; k0+=32){
      bf16x8 a = *reinterpret_cast<const bf16x8*>(sZ + r16*SZS + k0 + kk);
      #pragma unroll
      for (int ct=0; ct<4; ct++){
        bf16x8 b = *reinterpret_cast<const bf16x8*>(wp + O_WCTXT + (cb+ct*16+r16)*256 + k0 + kk);
        acc[ct] = mfma16(a, b, acc[ct]);
      }
    }
    #pragma unroll
    for (int ct=0; ct<4; ct++)
      #pragma unroll
      for (int v=0; v<4; v++)
        cpv[ct][v] = tanh_(acc[ct][v] + b_ctx[cb + ct*16 + r16]);
  }
  __syncthreads();   // all reads of ctx_ln done
  #pragma unroll
  for (int ct=0; ct<4; ct++)
    #pragma unroll
    for (int v=0; v<4; v++){
      int col = cb + ct*16 + r16;
      sZ[(vr4+v)*SZS + col] = f2bf(cpv[ct][v]);
    }
  __syncthreads();

  // ---- Phase J: alpha = sigmoid([gru_out|ctx_p]@W_gate + b_gate); combine -> sF
  {
    f32x4 acc[4] = {};
    for (int k0=0; k0<512; k0+=32){
      bf16x8 a;
      if (k0 < 256) a = frag_f32(sGO + r16*SGOS + k0 + kk);
      else          a = *reinterpret_cast<const bf16x8*>(sZ + r16*SZS + (k0-256) + kk);
      #pragma unroll
      for (int ct=0; ct<4; ct++){
        bf16x8 b = *reinterpret_cast<const bf16x8*>(wp + O_WGT + (cb+ct*16+r16)*512 + k0 + kk);
        acc[ct] = mfma16(a, b, acc[ct]);
      }
    }
    #pragma unroll
    for (int ct=0; ct<4; ct++)
      #pragma unroll
      for (int v=0; v<4; v++){
        int lrow = vr4 + v, col = cb + ct*16 + r16;
        float al = sigm(acc[ct][v] + b_gate[col]);
        float go = sGO[lrow*SGOS + col];
        sF[lrow*SFS + col] = (1.f-al)*go + al*cpv[ct][v];
      }
  }
  __syncthreads();

  // ---- LN2 (wave-local) : sF -> d_out h_corr
  {
    int r = tid >> 4, q = tid & 15;
    float s1=0.f, s2=0.f;
    #pragma unroll
    for (int ii=0; ii<16; ii++){ float v = sF[r*SFS + q*16 + ii]; s1+=v; s2+=v*v; }
    #pragma unroll
    for (int off=8; off; off>>=1){ s1 += __shfl_xor(s1,off); s2 += __shfl_xor(s2,off); }
    float mu = s1*(1.f/256.f);
    float rs = rsqrtf(fmaxf(s2*(1.f/256.f) - mu*mu, 0.f) + 1e-3f);
    float* od = d_out + (size_t)(row0+r)*256;
    #pragma unroll
    for (int ii=0; ii<16; ii+=4){
      float4 o;
      int c = q*16 + ii;
      o.x = (sF[r*SFS+c+0]-mu)*rs*g_out[c+0] + beta_out[c+0];
      o.y = (sF[r*SFS+c+1]-mu)*rs*g_out[c+1] + beta_out[c+1];
      o.z = (sF[r*SFS+c+2]-mu)*rs*g_out[c+2] + beta_out[c+2];
      o.w = (sF[r*SFS+c+3]-mu)*rs*g_out[c+3] + beta_out[c+3];
      *reinterpret_cast<float4*>(od + c) = o;
    }
  }
}

extern "C" void kernel_launch(void* const* d_in, const int* in_sizes, int n_in,
                              void* d_out, int out_size, void* d_ws, size_t ws_size,
                              hipStream_t stream)
{
  const float* inputs   = (const float*)d_in[0];
  const float* h_prev   = (const float*)d_in[1];
  const float* memory   = (const float*)d_in[2];
  const float* W_in     = (const float*)d_in[3];
  const float* b_in     = (const float*)d_in[4];
  const float* gru_k    = (const float*)d_in[5];
  const float* gru_rk   = (const float*)d_in[6];
  const float* gru_b    = (const float*)d_in[7];
  const float* Wq       = (const float*)d_in[8];
  const float* bq       = (const float*)d_in[9];
  const float* Wk       = (const float*)d_in[10];
  // d_in[11] = bk: constant over m under softmax -> cancels
  const float* Wv       = (const float*)d_in[12];
  const float* bv       = (const float*)d_in[13];
  const float* Wo       = (const float*)d_in[14];
  const float* bo       = (const float*)d_in[15];
  const float* g_attn   = (const float*)d_in[16];
  const float* beta_attn= (const float*)d_in[17];
  const float* g_out    = (const float*)d_in[18];
  const float* beta_out = (const float*)d_in[19];
  const float* W_ctx    = (const float*)d_in[20];
  const float* b_ctx    = (const float*)d_in[21];
  const float* W_gate   = (const float*)d_in[22];
  const float* b_gate   = (const float*)d_in[23];
  const float* W_mem    = (const float*)d_in[24];
  const float* b_mem    = (const float*)d_in[25];

  short* wp  = (short*)d_ws;
  float* out = (float*)d_out;

  k_prep<<<W_TOTAL/256, 256, 0, stream>>>(W_in, gru_k, gru_rk, Wq, Wk, Wv, Wo,
                                          W_ctx, W_gate, W_mem, wp);
  k_fused<<<BN/16, 256, 0, stream>>>(inputs, h_prev, memory,
                                     b_in, gru_b, bq, b_mem, bv, bo,
                                     g_attn, beta_attn, b_ctx, b_gate,
                                     g_out, beta_out, wp, out);
}

// Round 4
// 357.835 us; speedup vs baseline: 1.0049x; 1.0049x over previous
//
#include <hip/hip_runtime.h>
#include <hip/hip_bf16.h>
#include <cstdint>
#include <cstddef>

#define BN 8192

typedef short bf16x8 __attribute__((ext_vector_type(8)));
typedef float f32x4 __attribute__((ext_vector_type(4)));

// ---- workspace layout: bf16 weight packs, B^T layout [n][k] unless noted ----
#define O_WINT   0         // [256][256]
#define O_GKT    65536     // [768][256]
#define O_GRKT   262144    // [768][256]
#define O_WQT    458752    // [256][256]
#define O_WK     524288    // native [d][h*64+dk]
#define O_WVT    589824    // [(h,dk)=256][256]
#define O_WOT    655360    // [256][256]
#define O_WCTXT  720896    // [256][256]
#define O_WGT    786432    // [256][512]
#define O_WMT    917504    // [256][256]
#define W_TOTAL  983040

// LDS strides (element units). All rows 16B-aligned; row-stride mod 128B = 16B
// -> consecutive r16 rows land on banks offset by 4 words => <=2-way conflict (free, m136).
#define SZS  264   // shorts: sZ tile [16][264]
#define SGOS 260   // floats: gru_out fp32 [16][260]
#define SQS  1032  // shorts: qk/wmem [16][1032]
#define SFS  260   // floats: sF (aliases sQK buffer)

__device__ __forceinline__ short f2bf(float x){
  unsigned u = __builtin_bit_cast(unsigned, x);
  u = (u + 0x7fffu + ((u >> 16) & 1u)) >> 16;
  return (short)u;
}
__device__ __forceinline__ float bf2f(short s){
  unsigned u = ((unsigned)(unsigned short)s) << 16;
  return __builtin_bit_cast(float, u);
}
__device__ __forceinline__ float sigm(float x){ return 1.f/(1.f+__expf(-x)); }
__device__ __forceinline__ float tanh_(float x){
  x = fminf(20.f, fmaxf(-20.f, x));
  float e = __expf(-2.f*x);
  return (1.f - e)/(1.f + e);
}
__device__ __forceinline__ f32x4 mfma16(bf16x8 a, bf16x8 b, f32x4 c){
  return __builtin_amdgcn_mfma_f32_16x16x32_bf16(a, b, c, 0, 0, 0);
}
// 8 consecutive fp32 -> bf16 frag (works for global or LDS pointers)
__device__ __forceinline__ bf16x8 frag_f32(const float* p){
  float4 a = *reinterpret_cast<const float4*>(p);
  float4 b = *reinterpret_cast<const float4*>(p+4);
  bf16x8 v;
  v[0]=f2bf(a.x); v[1]=f2bf(a.y); v[2]=f2bf(a.z); v[3]=f2bf(a.w);
  v[4]=f2bf(b.x); v[5]=f2bf(b.y); v[6]=f2bf(b.z); v[7]=f2bf(b.w);
  return v;
}

// ============================ K0: weight pack ============================
__global__ __launch_bounds__(256) void k_prep(
    const float* __restrict__ W_in, const float* __restrict__ gru_k,
    const float* __restrict__ gru_rk, const float* __restrict__ Wq,
    const float* __restrict__ Wk, const float* __restrict__ Wv,
    const float* __restrict__ Wo, const float* __restrict__ W_ctx,
    const float* __restrict__ W_gate, const float* __restrict__ W_mem,
    short* __restrict__ wp)
{
  int idx = blockIdx.x*256 + threadIdx.x;
  if (idx < 65536){ int n=idx>>8, k=idx&255; wp[O_WINT+idx]=f2bf(W_in[k*256+n]); return; }
  idx -= 65536;
  if (idx < 196608){ int n=idx>>8, k=idx&255; wp[O_GKT+idx]=f2bf(gru_k[k*768+n]); return; }
  idx -= 196608;
  if (idx < 196608){ int n=idx>>8, k=idx&255; wp[O_GRKT+idx]=f2bf(gru_rk[k*768+n]); return; }
  idx -= 196608;
  if (idx < 65536){ int n=idx>>8, k=idx&255; wp[O_WQT+idx]=f2bf(Wq[k*256+n]); return; }
  idx -= 65536;
  if (idx < 65536){ wp[O_WK+idx]=f2bf(Wk[idx]); return; }
  idx -= 65536;
  if (idx < 65536){ int n=idx>>8, k=idx&255; wp[O_WVT+idx]=f2bf(Wv[k*256+n]); return; }
  idx -= 65536;
  if (idx < 65536){ int n=idx>>8, k=idx&255; wp[O_WOT+idx]=f2bf(Wo[k*256+n]); return; }
  idx -= 65536;
  if (idx < 65536){ int n=idx>>8, k=idx&255; wp[O_WCTXT+idx]=f2bf(W_ctx[k*256+n]); return; }
  idx -= 65536;
  if (idx < 131072){ int n=idx>>9, k=idx&511; wp[O_WGT+idx]=f2bf(W_gate[k*256+n]); return; }
  idx -= 131072;
  if (idx < 65536){ int n=idx>>8, k=idx&255; wp[O_WMT+idx]=f2bf(W_mem[k*256+n]); }
}

// ======== K1: fully fused cell, 16 rows/block, 8 waves (512 thr) ========
__global__ __launch_bounds__(512, 4) void k_fused(
    const float* __restrict__ inputs, const float* __restrict__ h_prev,
    const float* __restrict__ mem,
    const float* __restrict__ b_in, const float* __restrict__ gru_b,
    const float* __restrict__ bq, const float* __restrict__ b_mem,
    const float* __restrict__ bv, const float* __restrict__ bo,
    const float* __restrict__ g_attn, const float* __restrict__ beta_attn,
    const float* __restrict__ b_ctx, const float* __restrict__ b_gate,
    const float* __restrict__ g_out, const float* __restrict__ beta_out,
    const short* __restrict__ wp, float* __restrict__ d_out)
{
  const int tid = threadIdx.x;
  const int wv = tid >> 6, lane = tid & 63;
  const int r16 = lane & 15, kk = (lane >> 4) * 8, vr4 = (lane >> 4) * 4;
  const int row0 = blockIdx.x * 16;
  const int cb = wv * 32;                 // 32 output cols per wave (2 ct tiles)

  __shared__ __attribute__((aligned(16))) short sZ[16*SZS];   // z_t -> q -> ctx -> ctx_ln -> ctx_p
  __shared__ __attribute__((aligned(16))) float sGO[16*SGOS]; // gru_out fp32
  __shared__ __attribute__((aligned(16))) short sQK[16*SQS];  // qk -> wmem; aliased by sF
  float* sF = (float*)sQK;                                    // fp32 scratch (context / h_pre)

  // ---- Phase A: z_t = inputs @ W_in + b_in -> sZ (bf16)
  {
    f32x4 acc[2] = {};
    for (int k0=0; k0<256; k0+=32){
      bf16x8 a = frag_f32(inputs + (size_t)(row0+r16)*256 + k0 + kk);
      #pragma unroll
      for (int ct=0; ct<2; ct++){
        bf16x8 b = *reinterpret_cast<const bf16x8*>(wp + O_WINT + (cb+ct*16+r16)*256 + k0 + kk);
        acc[ct] = mfma16(a, b, acc[ct]);
      }
    }
    #pragma unroll
    for (int ct=0; ct<2; ct++)
      #pragma unroll
      for (int v=0; v<4; v++){
        int col = cb + ct*16 + r16;
        sZ[(vr4+v)*SZS + col] = f2bf(acc[ct][v] + b_in[col]);
      }
  }
  __syncthreads();

  // ---- Phase B: new_entry = z_t @ W_mem + b_mem -> out memory slot 9
  {
    f32x4 acc[2] = {};
    for (int k0=0; k0<256; k0+=32){
      bf16x8 a = *reinterpret_cast<const bf16x8*>(sZ + r16*SZS + k0 + kk);
      #pragma unroll
      for (int ct=0; ct<2; ct++){
        bf16x8 b = *reinterpret_cast<const bf16x8*>(wp + O_WMT + (cb+ct*16+r16)*256 + k0 + kk);
        acc[ct] = mfma16(a, b, acc[ct]);
      }
    }
    float* om = d_out + (size_t)BN*256;
    #pragma unroll
    for (int ct=0; ct<2; ct++)
      #pragma unroll
      for (int v=0; v<4; v++){
        int col = cb + ct*16 + r16;
        om[(size_t)(row0+vr4+v)*2560 + 2304 + col] = acc[ct][v] + b_mem[col];
      }
  }

  // ---- Phase C: GRU (reset_after) -> sGO (fp32 LDS)
  #pragma unroll
  for (int ct=0; ct<2; ct++){
    const int c = cb + ct*16;
    f32x4 az = {}, arr = {}, ax = {}, ah = {};
    for (int k0=0; k0<256; k0+=32){
      bf16x8 aZ = *reinterpret_cast<const bf16x8*>(sZ + r16*SZS + k0 + kk);
      bf16x8 aH = frag_f32(h_prev + (size_t)(row0+r16)*256 + k0 + kk);
      bf16x8 bz1 = *reinterpret_cast<const bf16x8*>(wp + O_GKT  + (c      +r16)*256 + k0 + kk);
      bf16x8 br1 = *reinterpret_cast<const bf16x8*>(wp + O_GKT  + (256+c  +r16)*256 + k0 + kk);
      bf16x8 bx1 = *reinterpret_cast<const bf16x8*>(wp + O_GKT  + (512+c  +r16)*256 + k0 + kk);
      bf16x8 bz2 = *reinterpret_cast<const bf16x8*>(wp + O_GRKT + (c      +r16)*256 + k0 + kk);
      bf16x8 br2 = *reinterpret_cast<const bf16x8*>(wp + O_GRKT + (256+c  +r16)*256 + k0 + kk);
      bf16x8 bh2 = *reinterpret_cast<const bf16x8*>(wp + O_GRKT + (512+c  +r16)*256 + k0 + kk);
      az  = mfma16(aZ, bz1, az);  az  = mfma16(aH, bz2, az);
      arr = mfma16(aZ, br1, arr); arr = mfma16(aH, br2, arr);
      ax  = mfma16(aZ, bx1, ax);
      ah  = mfma16(aH, bh2, ah);
    }
    #pragma unroll
    for (int v=0; v<4; v++){
      int lrow = vr4 + v, grow = row0 + lrow, col = c + r16;
      float z  = sigm(az[v]  + gru_b[col]     + gru_b[768+col]);
      float r  = sigm(arr[v] + gru_b[256+col] + gru_b[768+256+col]);
      float hc = tanh_(ax[v] + gru_b[512+col] + r*(ah[v] + gru_b[768+512+col]));
      float hp = h_prev[(size_t)grow*256 + col];
      sGO[lrow*SGOS + col] = z*hp + (1.f - z)*hc;
    }
  }
  __syncthreads();   // sGO ready; all reads of sZ(z_t) done

  // ---- Phase D: q = gru_out @ Wq + bq -> sZ (reuse)
  {
    f32x4 acc[2] = {};
    for (int k0=0; k0<256; k0+=32){
      bf16x8 a = frag_f32(sGO + r16*SGOS + k0 + kk);
      #pragma unroll
      for (int ct=0; ct<2; ct++){
        bf16x8 b = *reinterpret_cast<const bf16x8*>(wp + O_WQT + (cb+ct*16+r16)*256 + k0 + kk);
        acc[ct] = mfma16(a, b, acc[ct]);
      }
    }
    #pragma unroll
    for (int ct=0; ct<2; ct++)
      #pragma unroll
      for (int v=0; v<4; v++){
        int col = cb + ct*16 + r16;
        sZ[(vr4+v)*SZS + col] = f2bf(acc[ct][v] + bq[col]);
      }
  }
  __syncthreads();

  // ---- Phase E: qk_h = q_h @ Wk_h^T -> sQK bf16 [16][4*256]
  // wave -> head h = wv&3, nb pair = (wv>>2)*2 + {0,1}
  {
    const int h = wv & 3, nbb = (wv >> 2) * 2;
    for (int nb2=0; nb2<2; nb2++){
      const int nb = nbb + nb2;
      f32x4 acc[4] = {};
      #pragma unroll
      for (int k0=0; k0<64; k0+=32){
        bf16x8 a = *reinterpret_cast<const bf16x8*>(sZ + r16*SZS + h*64 + k0 + kk);
        #pragma unroll
        for (int ct=0; ct<4; ct++){
          bf16x8 b = *reinterpret_cast<const bf16x8*>(wp + O_WK + (nb*64+ct*16+r16)*256 + h*64 + k0 + kk);
          acc[ct] = mfma16(a, b, acc[ct]);
        }
      }
      #pragma unroll
      for (int ct=0; ct<4; ct++)
        #pragma unroll
        for (int v=0; v<4; v++){
          int d = nb*64 + ct*16 + r16;
          sQK[(vr4+v)*SQS + h*256 + d] = f2bf(acc[ct][v]);
        }
    }
  }
  __syncthreads();

  // ---- Phase F: scores/softmax/wmem + memory shift (2 rows per wave)
  for (int i=0; i<2; i++){
    const int rr = wv*2 + i;
    const float* mrow = mem + (size_t)(row0+rr)*2560;
    float* orow = d_out + (size_t)BN*256 + (size_t)(row0+rr)*2560;

    float qv[4][4];
    #pragma unroll
    for (int h=0; h<4; h++){
      short4 s = *reinterpret_cast<const short4*>(sQK + rr*SQS + h*256 + lane*4);
      qv[h][0]=bf2f(s.x); qv[h][1]=bf2f(s.y); qv[h][2]=bf2f(s.z); qv[h][3]=bf2f(s.w);
    }
    float4 mv[10];
    float sc[10][4];
    #pragma unroll
    for (int m=0; m<10; m++){
      mv[m] = *reinterpret_cast<const float4*>(mrow + m*256 + lane*4);
      if (m >= 1) *reinterpret_cast<float4*>(orow + (m-1)*256 + lane*4) = mv[m];  // shift
      #pragma unroll
      for (int h=0; h<4; h++){
        float p = qv[h][0]*mv[m].x + qv[h][1]*mv[m].y + qv[h][2]*mv[m].z + qv[h][3]*mv[m].w;
        p += __shfl_xor(p,32); p += __shfl_xor(p,16); p += __shfl_xor(p,8);
        p += __shfl_xor(p,4);  p += __shfl_xor(p,2);  p += __shfl_xor(p,1);
        sc[m][h] = p * 0.125f;
      }
    }
    #pragma unroll
    for (int h=0; h<4; h++){
      float mx = sc[0][h];
      #pragma unroll
      for (int m=1; m<10; m++) mx = fmaxf(mx, sc[m][h]);
      float s = 0.f;
      #pragma unroll
      for (int m=0; m<10; m++){ float e = __expf(sc[m][h]-mx); sc[m][h]=e; s+=e; }
      float inv = 1.f/s;
      #pragma unroll
      for (int m=0; m<10; m++) sc[m][h] *= inv;
    }
    float w4[4][4] = {};
    #pragma unroll
    for (int m=0; m<10; m++)
      #pragma unroll
      for (int h=0; h<4; h++){
        w4[h][0] += sc[m][h]*mv[m].x; w4[h][1] += sc[m][h]*mv[m].y;
        w4[h][2] += sc[m][h]*mv[m].z; w4[h][3] += sc[m][h]*mv[m].w;
      }
    #pragma unroll
    for (int h=0; h<4; h++){
      short4 o; o.x=f2bf(w4[h][0]); o.y=f2bf(w4[h][1]); o.z=f2bf(w4[h][2]); o.w=f2bf(w4[h][3]);
      *reinterpret_cast<short4*>(sQK + rr*SQS + h*256 + lane*4) = o;  // wmem over dead qk
    }
  }
  __syncthreads();

  // ---- Phase G: ctx_h = wmem_h @ Wv_h + bv -> sZ
  // wave -> head h = wv>>1; within-head 32-col half = (wv&1)*32
  {
    const int h = wv >> 1;
    const int gc = h*64 + (wv&1)*32;
    f32x4 acc[2] = {};
    for (int k0=0; k0<256; k0+=32){
      bf16x8 a = *reinterpret_cast<const bf16x8*>(sQK + r16*SQS + h*256 + k0 + kk);
      #pragma unroll
      for (int ct=0; ct<2; ct++){
        bf16x8 b = *reinterpret_cast<const bf16x8*>(wp + O_WVT + (gc+ct*16+r16)*256 + k0 + kk);
        acc[ct] = mfma16(a, b, acc[ct]);
      }
    }
    #pragma unroll
    for (int ct=0; ct<2; ct++)
      #pragma unroll
      for (int v=0; v<4; v++){
        int col = gc + ct*16 + r16;
        sZ[(vr4+v)*SZS + col] = f2bf(acc[ct][v] + bv[col]);
      }
  }
  __syncthreads();

  // ---- Phase H: context = ctx @ Wo + bo -> sF (fp32; aliases sQK, wmem dead)
  {
    f32x4 acc[2] = {};
    for (int k0=0; k0<256; k0+=32){
      bf16x8 a = *reinterpret_cast<const bf16x8*>(sZ + r16*SZS + k0 + kk);
      #pragma unroll
      for (int ct=0; ct<2; ct++){
        bf16x8 b = *reinterpret_cast<const bf16x8*>(wp + O_WOT + (cb+ct*16+r16)*256 + k0 + kk);
        acc[ct] = mfma16(a, b, acc[ct]);
      }
    }
    #pragma unroll
    for (int ct=0; ct<2; ct++)
      #pragma unroll
      for (int v=0; v<4; v++){
        int col = cb + ct*16 + r16;
        sF[(vr4+v)*SFS + col] = acc[ct][v] + bo[col];
      }
  }
  __syncthreads();

  // ---- LN1 (32 lanes per row): sF -> sZ (bf16 ctx_ln)
  {
    int r = tid >> 5, q = tid & 31;
    float s1=0.f, s2=0.f;
    #pragma unroll
    for (int ii=0; ii<8; ii++){ float v = sF[r*SFS + q*8 + ii]; s1+=v; s2+=v*v; }
    #pragma unroll
    for (int off=16; off; off>>=1){ s1 += __shfl_xor(s1,off); s2 += __shfl_xor(s2,off); }
    float mu = s1*(1.f/256.f);
    float rs = rsqrtf(fmaxf(s2*(1.f/256.f) - mu*mu, 0.f) + 1e-3f);
    #pragma unroll
    for (int ii=0; ii<8; ii++){
      int c = q*8 + ii;
      sZ[r*SZS + c] = f2bf((sF[r*SFS + c]-mu)*rs*g_attn[c] + beta_attn[c]);
    }
  }
  __syncthreads();

  // ---- Phase I: ctx_p = tanh(ctx_ln @ W_ctx + b_ctx) -> regs, then sZ
  f32x4 cpv[2];
  {
    f32x4 acc[2] = {};
    for (int k0=0; k0<256; k0+=32){
      bf16x8 a = *reinterpret_cast<const bf16x8*>(sZ + r16*SZS + k0 + kk);
      #pragma unroll
      for (int ct=0; ct<2; ct++){
        bf16x8 b = *reinterpret_cast<const bf16x8*>(wp + O_WCTXT + (cb+ct*16+r16)*256 + k0 + kk);
        acc[ct] = mfma16(a, b, acc[ct]);
      }
    }
    #pragma unroll
    for (int ct=0; ct<2; ct++)
      #pragma unroll
      for (int v=0; v<4; v++)
        cpv[ct][v] = tanh_(acc[ct][v] + b_ctx[cb + ct*16 + r16]);
  }
  __syncthreads();   // all reads of ctx_ln done
  #pragma unroll
  for (int ct=0; ct<2; ct++)
    #pragma unroll
    for (int v=0; v<4; v++){
      int col = cb + ct*16 + r16;
      sZ[(vr4+v)*SZS + col] = f2bf(cpv[ct][v]);
    }
  __syncthreads();

  // ---- Phase J: alpha = sigmoid([gru_out|ctx_p]@W_gate + b_gate); combine -> sF
  {
    f32x4 acc[2] = {};
    for (int k0=0; k0<512; k0+=32){
      bf16x8 a;
      if (k0 < 256) a = frag_f32(sGO + r16*SGOS + k0 + kk);
      else          a = *reinterpret_cast<const bf16x8*>(sZ + r16*SZS + (k0-256) + kk);
      #pragma unroll
      for (int ct=0; ct<2; ct++){
        bf16x8 b = *reinterpret_cast<const bf16x8*>(wp + O_WGT + (cb+ct*16+r16)*512 + k0 + kk);
        acc[ct] = mfma16(a, b, acc[ct]);
      }
    }
    #pragma unroll
    for (int ct=0; ct<2; ct++)
      #pragma unroll
      for (int v=0; v<4; v++){
        int lrow = vr4 + v, col = cb + ct*16 + r16;
        float al = sigm(acc[ct][v] + b_gate[col]);
        float go = sGO[lrow*SGOS + col];
        sF[lrow*SFS + col] = (1.f-al)*go + al*cpv[ct][v];
      }
  }
  __syncthreads();

  // ---- LN2 (32 lanes per row): sF -> d_out h_corr
  {
    int r = tid >> 5, q = tid & 31;
    float s1=0.f, s2=0.f;
    #pragma unroll
    for (int ii=0; ii<8; ii++){ float v = sF[r*SFS + q*8 + ii]; s1+=v; s2+=v*v; }
    #pragma unroll
    for (int off=16; off; off>>=1){ s1 += __shfl_xor(s1,off); s2 += __shfl_xor(s2,off); }
    float mu = s1*(1.f/256.f);
    float rs = rsqrtf(fmaxf(s2*(1.f/256.f) - mu*mu, 0.f) + 1e-3f);
    float* od = d_out + (size_t)(row0+r)*256;
    #pragma unroll
    for (int ii=0; ii<8; ii+=4){
      float4 o;
      int c = q*8 + ii;
      o.x = (sF[r*SFS+c+0]-mu)*rs*g_out[c+0] + beta_out[c+0];
      o.y = (sF[r*SFS+c+1]-mu)*rs*g_out[c+1] + beta_out[c+1];
      o.z = (sF[r*SFS+c+2]-mu)*rs*g_out[c+2] + beta_out[c+2];
      o.w = (sF[r*SFS+c+3]-mu)*rs*g_out[c+3] + beta_out[c+3];
      *reinterpret_cast<float4*>(od + c) = o;
    }
  }
}

extern "C" void kernel_launch(void* const* d_in, const int* in_sizes, int n_in,
                              void* d_out, int out_size, void* d_ws, size_t ws_size,
                              hipStream_t stream)
{
  const float* inputs   = (const float*)d_in[0];
  const float* h_prev   = (const float*)d_in[1];
  const float* memory   = (const float*)d_in[2];
  const float* W_in     = (const float*)d_in[3];
  const float* b_in     = (const float*)d_in[4];
  const float* gru_k    = (const float*)d_in[5];
  const float* gru_rk   = (const float*)d_in[6];
  const float* gru_b    = (const float*)d_in[7];
  const float* Wq       = (const float*)d_in[8];
  const float* bq       = (const float*)d_in[9];
  const float* Wk       = (const float*)d_in[10];
  // d_in[11] = bk: constant over m under softmax -> cancels
  const float* Wv       = (const float*)d_in[12];
  const float* bv       = (const float*)d_in[13];
  const float* Wo       = (const float*)d_in[14];
  const float* bo       = (const float*)d_in[15];
  const float* g_attn   = (const float*)d_in[16];
  const float* beta_attn= (const float*)d_in[17];
  const float* g_out    = (const float*)d_in[18];
  const float* beta_out = (const float*)d_in[19];
  const float* W_ctx    = (const float*)d_in[20];
  const float* b_ctx    = (const float*)d_in[21];
  const float* W_gate   = (const float*)d_in[22];
  const float* b_gate   = (const float*)d_in[23];
  const float* W_mem    = (const float*)d_in[24];
  const float* b_mem    = (const float*)d_in[25];

  short* wp  = (short*)d_ws;
  float* out = (float*)d_out;

  k_prep<<<W_TOTAL/256, 256, 0, stream>>>(W_in, gru_k, gru_rk, Wq, Wk, Wv, Wo,
                                          W_ctx, W_gate, W_mem, wp);
  k_fused<<<BN/16, 512, 0, stream>>>(inputs, h_prev, memory,
                                     b_in, gru_b, bq, b_mem, bv, bo,
                                     g_attn, beta_attn, b_ctx, b_gate,
                                     g_out, beta_out, wp, out);
}